// Round 6
// baseline (340.451 us; speedup 1.0000x reference)
//
#include <hip/hip_runtime.h>
#include <hip/hip_bf16.h>

#define B_ 4
#define L_ 2048
#define DM 1024
#define DI 2048
#define NR (B_ * L_)   // 8192 rows
#define DTR 64
#define NCHUNK 32
#define CHUNK 64
#define CCONV 16       // conv time-chunk (16 -> 1024 blocks, BW-saturating)
#define KSLICE 8       // split-K slices for GEMM2

typedef __attribute__((ext_vector_type(8))) short short8;
typedef __attribute__((ext_vector_type(4))) float floatx4;
typedef __attribute__((ext_vector_type(4))) int int4v;
typedef __attribute__((ext_vector_type(4))) unsigned short ushort4v;

// bf16 <-> f32 (bf16->f32 is exact widening; f32->bf16 uses RNE via __float2bfloat16)
__device__ __forceinline__ float bf2f(unsigned short u) {
    return __uint_as_float(((unsigned)u) << 16);
}
__device__ __forceinline__ unsigned short f2bf(float f) {
    __hip_bfloat16 h = __float2bfloat16(f);
    return *reinterpret_cast<unsigned short*>(&h);
}

// ---------------- workspace layout (bytes) ----------------
static constexpr size_t OFF_SCAL = 0;                                    // 4 f32 scales
static constexpr size_t OFF_PART = 256;                                  // 4*256 f32 partials
static constexpr size_t OFF_XN   = 4608;                                 // xn i8 [NR,DM] (8 MB of 16 MB region)
static constexpr size_t OFF_TIN  = OFF_XN   + (size_t)NR * DM * 2;       // T_in i8 [4096,1024] (4 MB of 8 MB region)
static constexpr size_t OFF_TX   = OFF_TIN  + (size_t)2 * DI * DM * 2;   // T_x bf16 [64,2048]
static constexpr size_t OFF_TDT  = OFF_TX   + (size_t)DTR * DI * 2;      // T_dt bf16 [2048,64]
static constexpr size_t OFF_TOUT = OFF_TDT  + (size_t)DI * DTR * 2;      // T_out bf16 [1024,2048]
static constexpr size_t OFF_XC   = OFF_TOUT + (size_t)DM * DI * 2;       // xc bf16 [NR,DI]
static constexpr size_t OFF_P2   = OFF_XC   + (size_t)NR * DI * 2;       // GEMM2 f32 partials [8,NR,64]
static constexpr size_t OFF_ZSP  = OFF_XC   + (size_t)NR * DI * 4;       // z raw bf16 [NR,DI]
static constexpr size_t OFF_XACT = OFF_ZSP  + (size_t)NR * DI * 2;       // sp(conv) bf16 [NR,DI]
static constexpr size_t OFF_DBL  = OFF_XACT + (size_t)NR * DI * 2;       // dbl bf16 [NR,64]
static constexpr size_t OFF_DEC  = OFF_DBL  + (size_t)NR * DTR * 2;      // decay u16 [NR,DI]
static constexpr size_t OFF_CA   = OFF_DEC  + (size_t)NR * DI * 2;       // chunk A f32 [B,32,DI]
static constexpr size_t OFF_CB   = OFF_CA   + (size_t)B_ * NCHUNK * DI * 4;
static constexpr size_t OFF_Y    = OFF_CB   + (size_t)B_ * NCHUNK * DI * 4; // y bf16 [NR,DI]
static constexpr size_t OFF_SROW = OFF_Y    + (size_t)NR * DI * 2;       // per-row xn scale f32 [NR]

// ---------------- async global->LDS (16B per lane, wave-uniform base rule) ----------------
__device__ __forceinline__ void async16(const void* g, void* l) {
    __builtin_amdgcn_global_load_lds(
        (const __attribute__((address_space(1))) unsigned int*)g,
        (__attribute__((address_space(3))) unsigned int*)l, 16, 0, 0);
}

// ---------------- scalar math (bit-faithful to reference) ----------------
__device__ __forceinline__ float pow2scale(float var) {
    float v = var + 1e-9f;
    float s = 1.0f;
    if (v >= 4.0f)     s = 0.5f;
    if (v >= 16.0f)    s = 0.25f;
    if (v >= 64.0f)    s = 0.125f;
    if (v >= 256.0f)   s = 0.0625f;
    if (v >= 1024.0f)  s = 0.03125f;
    if (v >= 4096.0f)  s = 0.015625f;
    if (v >= 16384.0f) s = 0.0078125f;
    if (v >= 65536.0f) s = 0.00390625f;
    if (v < 1.0f)    s = 1.0f;
    if (v < 0.25f)   s = 2.0f;
    if (v < 0.0625f) s = 4.0f;
    return s;
}

// NOTE: must stay bit-faithful — the reference's Newton rsqrt genuinely diverges
// for y=x^2+4 in (12,16] (seed 0.5, clip to 1e-6 -> sp(x)=x/2 there). Do NOT
// replace with true rsqrt.
__device__ __forceinline__ float squareplus_f(float x) {
    float y = fminf(fmaxf(x * x + 4.0f, 1e-6f), 1e6f);
    float r = (y > 16.0f) ? 0.125f : 0.5f;
    if (y > 64.0f)  r = 0.0625f;
    if (y > 256.0f) r = 0.03125f;
    if (y < 4.0f)   r = 1.0f;
    if (y < 1.0f)   r = 2.0f;
    if (y < 0.25f)  r = 4.0f;
#pragma unroll
    for (int i = 0; i < 3; ++i) {
        r = r * (1.5f - 0.5f * y * r * r);
        r = fminf(fmaxf(r, 1e-6f), 1e3f);
    }
    float s = fminf(fmaxf(y * r, 0.0f), 1e3f);
    return 0.5f * (x + s);
}

__device__ __forceinline__ float block_reduce_sum(float v) {
    __shared__ float sm[4];
#pragma unroll
    for (int o = 32; o > 0; o >>= 1) v += __shfl_down(v, o, 64);
    int w = threadIdx.x >> 6;
    __syncthreads();
    if ((threadIdx.x & 63) == 0) sm[w] = v;
    __syncthreads();
    return (sm[0] + sm[1]) + (sm[2] + sm[3]);
}

__device__ __forceinline__ float block_reduce_max(float v) {
    __shared__ float smx[4];
#pragma unroll
    for (int o = 32; o > 0; o >>= 1) v = fmaxf(v, __shfl_down(v, o, 64));
    int w = threadIdx.x >> 6;
    __syncthreads();
    if ((threadIdx.x & 63) == 0) smx[w] = v;
    __syncthreads();
    return fmaxf(fmaxf(smx[0], smx[1]), fmaxf(smx[2], smx[3]));
}

// ---------------- fused weight-scale partials (all 4 weights, one launch, float4) ----------------
__global__ __launch_bounds__(256) void k_abs_all(const float* __restrict__ W0,
                                                 const float* __restrict__ W1,
                                                 const float* __restrict__ W2,
                                                 const float* __restrict__ W3,
                                                 float* __restrict__ part) {
    const int w = blockIdx.y;
    const float* W = (w == 0) ? W0 : (w == 1) ? W1 : (w == 2) ? W2 : W3;
    const int n4 = ((w == 0) ? 2 * DI * DM : (w == 1) ? 96 * DI : (w == 2) ? DI * DTR : DM * DI) / 4;
    const float4* W4 = (const float4*)W;
    float s = 0.f;
    for (int i = blockIdx.x * 256 + threadIdx.x; i < n4; i += 256 * 256) {
        float4 v = W4[i];
        s += fabsf(v.x) + fabsf(v.y) + fabsf(v.z) + fabsf(v.w);
    }
    float t = block_reduce_sum(s);
    if (threadIdx.x == 0) part[w * 256 + blockIdx.x] = t;
}

__global__ __launch_bounds__(256) void k_finalize(const float* __restrict__ part,
                                                  float* __restrict__ scal) {
    const float counts[4] = {(float)(2 * DI * DM), (float)(96 * DI),
                             (float)(DI * DTR), (float)(DM * DI)};
    for (int w = 0; w < 4; ++w) {
        float s = block_reduce_sum(part[w * 256 + threadIdx.x]);
        if (threadIdx.x == 0) scal[w] = s / counts[w] + 1e-8f;
    }
}

// ---------------- fused ternary quantization ----------------
// W_in -> i8 (exact ternary); W_x/W_dt/W_out -> bf16 (exact ternary)
// block segments (1024 elems/block): W_in 4096 | W_x[:64] 128 | W_dt 128 | W_out 2048 = 6400
__global__ __launch_bounds__(256) void k_quant_all(
    const float* __restrict__ W0, const float* __restrict__ W1,
    const float* __restrict__ W2, const float* __restrict__ W3,
    const float* __restrict__ scal,
    signed char* __restrict__ T0, __hip_bfloat16* __restrict__ T1,
    __hip_bfloat16* __restrict__ T2, __hip_bfloat16* __restrict__ T3) {
    int b = blockIdx.x;
    if (b < 4096) {
        int i = b * 1024 + threadIdx.x * 4;
        float inv = 1.0f / scal[0];
        float4 v = *(const float4*)(W0 + i);
        int q0 = (int)fmaxf(-1.0f, fminf(1.0f, rintf(v.x * inv)));
        int q1 = (int)fmaxf(-1.0f, fminf(1.0f, rintf(v.y * inv)));
        int q2 = (int)fmaxf(-1.0f, fminf(1.0f, rintf(v.z * inv)));
        int q3 = (int)fmaxf(-1.0f, fminf(1.0f, rintf(v.w * inv)));
        unsigned int packed = (q0 & 255) | ((q1 & 255) << 8) | ((q2 & 255) << 16) | ((q3 & 255) << 24);
        *reinterpret_cast<unsigned int*>(&T0[i]) = packed;
        return;
    }
    const float* W; const float* sp; __hip_bfloat16* T; int off;
    if (b < 4224)      { W = W1; sp = scal + 1; T = T1; off = b - 4096; }
    else if (b < 4352) { W = W2; sp = scal + 2; T = T2; off = b - 4224; }
    else               { W = W3; sp = scal + 3; T = T3; off = b - 4352; }
    int i = off * 1024 + threadIdx.x * 4;
    float inv = 1.0f / (*sp);
    float4 v = *(const float4*)(W + i);
    __hip_bfloat16 t[4];
    t[0] = __float2bfloat16(fmaxf(-1.0f, fminf(1.0f, rintf(v.x * inv))));
    t[1] = __float2bfloat16(fmaxf(-1.0f, fminf(1.0f, rintf(v.y * inv))));
    t[2] = __float2bfloat16(fmaxf(-1.0f, fminf(1.0f, rintf(v.z * inv))));
    t[3] = __float2bfloat16(fmaxf(-1.0f, fminf(1.0f, rintf(v.w * inv))));
    *reinterpret_cast<uint2*>(&T[i]) = *reinterpret_cast<uint2*>(t);
}

// ---------------- bitshift_norm -> per-row i8 quantized xn + row scale ----------------
__global__ __launch_bounds__(256) void k_norm(const float* __restrict__ x,
                                              const float* __restrict__ gamma,
                                              const float* __restrict__ step,
                                              signed char* __restrict__ xn8,
                                              float* __restrict__ srow) {
    int row = blockIdx.x;
    int tid = threadIdx.x;
    float4 v4 = ((const float4*)(x + (size_t)row * DM))[tid];
    float s = (v4.x + v4.y) + (v4.z + v4.w);
    float mean = block_reduce_sum(s) * (1.0f / DM);
    float d0 = v4.x - mean, d1 = v4.y - mean, d2 = v4.z - mean, d3 = v4.w - mean;
    float vv = d0 * d0 + d1 * d1 + d2 * d2 + d3 * d3;
    float var = block_reduce_sum(vv) * (1.0f / DM);
    float sc = pow2scale(var) * step[0];
    float4 g = ((const float4*)gamma)[tid];
    float w0 = d0 * sc * g.x, w1 = d1 * sc * g.y, w2 = d2 * sc * g.z, w3 = d3 * sc * g.w;
    float am = fmaxf(fmaxf(fabsf(w0), fabsf(w1)), fmaxf(fabsf(w2), fabsf(w3)));
    am = block_reduce_max(am);
    float sr = (am > 0.f) ? am * (1.0f / 127.0f) : 1.0f;
    float inv = 1.0f / sr;
    if (tid == 0) srow[row] = sr;
    int q0 = (int)rintf(w0 * inv), q1 = (int)rintf(w1 * inv);
    int q2 = (int)rintf(w2 * inv), q3 = (int)rintf(w3 * inv);
    unsigned int packed = (q0 & 255) | ((q1 & 255) << 8) | ((q2 & 255) << 16) | ((q3 & 255) << 24);
    ((unsigned int*)xn8)[row * 256 + tid] = packed;
}

// ---------------- GEMM1 (i8): 256x256 tile, 8-phase schedule (proven 63.5 us; NO reg reuse —
// the reuse variant regressed: clumped ds_reads serialize an lgkm drain at the phase head) ----
// C = xn8[8192,1024] @ Tin8[4096,1024]^T ; epilogue col<DI -> xc bf16, col>=DI -> z bf16
// 512 thr = 8 waves (2M x 4N). K-tile = 128 i8. LDS = 2 dbuf x (A,B) x 256row x 128B = 128 KiB.
// XOR slot-swizzle both sides. Stage slots per kt: P1:(kt+1).Ah1 P2:(kt+1).Bh0 P3:(kt+2).Ah0
// P4:(kt+2).Bh1 + vmcnt(4) (newest 4 = kt+2's stages).
__device__ __forceinline__ void stage128(const signed char* __restrict__ G, int base0,
                                         int ktile, signed char* lds, int half, int tid) {
#pragma unroll
    for (int r = 0; r < 2; ++r) {
        int slot = r * 512 + tid;
        int rih = slot >> 3, sl = slot & 7;
        async16(&G[(size_t)(base0 + half * 128 + rih) * DM + (size_t)ktile * 128 + ((sl ^ (rih & 7)) << 4)],
                &lds[half * 16384 + slot * 16]);
    }
}

#define G1_PHASE(QM, QN, STAGE, LASTOP)                                              \
    {                                                                                \
        int4v af[4][2], bfv[2][2];                                                   \
        _Pragma("unroll") for (int f = 0; f < 4; ++f) {                              \
            int rb = (QM) * 128 + f * 32 + wr * 16 + r16;                            \
            _Pragma("unroll") for (int kc = 0; kc < 2; ++kc)                         \
                af[f][kc] = *reinterpret_cast<const int4v*>(                         \
                    &curA[rb * 128 + (((kc * 4 + quad) ^ (rb & 7)) << 4)]);          \
        }                                                                            \
        _Pragma("unroll") for (int f = 0; f < 2; ++f) {                              \
            int cb = (QN) * 128 + f * 64 + wc * 16 + r16;                            \
            _Pragma("unroll") for (int kc = 0; kc < 2; ++kc)                         \
                bfv[f][kc] = *reinterpret_cast<const int4v*>(                        \
                    &curB[cb * 128 + (((kc * 4 + quad) ^ (cb & 7)) << 4)]);          \
        }                                                                            \
        STAGE;                                                                       \
        __builtin_amdgcn_s_barrier();                                                \
        __builtin_amdgcn_s_setprio(1);                                               \
        _Pragma("unroll") for (int f = 0; f < 4; ++f)                                \
        _Pragma("unroll") for (int g = 0; g < 2; ++g)                                \
        _Pragma("unroll") for (int kc = 0; kc < 2; ++kc)                             \
            acc[(QM) * 4 + f][(QN) * 2 + g] = __builtin_amdgcn_mfma_i32_16x16x64_i8( \
                af[f][kc], bfv[g][kc], acc[(QM) * 4 + f][(QN) * 2 + g], 0, 0, 0);    \
        __builtin_amdgcn_s_setprio(0);                                               \
        LASTOP;                                                                      \
        __builtin_amdgcn_s_barrier();                                                \
    }

__global__ __launch_bounds__(512) void k_gemm1_i8_8ph(
    const signed char* __restrict__ A, const signed char* __restrict__ Bw,
    const float* __restrict__ s_ptr, const float* __restrict__ srow,
    __hip_bfloat16* __restrict__ o_xc, __hip_bfloat16* __restrict__ o_z) {
    __shared__ __align__(16) signed char sA[2][32768];  // [dbuf][half*16384 + row*128 + slot*16]
    __shared__ __align__(16) signed char sB[2][32768];
    const int tid = threadIdx.x;
    const int lane = tid & 63, wid = tid >> 6;
    const int wr = wid >> 2, wc = wid & 3;      // 2 x 4 waves
    const int r16 = lane & 15, quad = lane >> 4;

    int nx = gridDim.x;                          // 16
    int bx = blockIdx.x, by = blockIdx.y;
    {
        int bid = by * nx + bx;
        int xcd = bid & 7, idx = bid >> 3;
        int npx = nx >> 3;                       // 2
        bx = xcd * npx + (idx % npx);
        by = idx / npx;
    }
    const int m0 = by * 256, n0 = bx * 256;

    int4v acc[8][4] = {};
    constexpr int KT = DM / 128;                 // 8 K-tiles

    // prologue: kt0 {Ah0,Bh1,Ah1,Bh0} + kt1 {Ah0,Bh1}  (12 loads); wait oldest 8 (= all of kt0)
    stage128(A,  m0, 0, sA[0], 0, tid);
    stage128(Bw, n0, 0, sB[0], 1, tid);
    stage128(A,  m0, 0, sA[0], 1, tid);
    stage128(Bw, n0, 0, sB[0], 0, tid);
    stage128(A,  m0, 1, sA[1], 0, tid);
    stage128(Bw, n0, 1, sB[1], 1, tid);
    __builtin_amdgcn_s_waitcnt(0x0F74);          // vmcnt(4)
    __builtin_amdgcn_s_barrier();

    for (int kt = 0; kt < KT; ++kt) {
        const signed char* curA = sA[kt & 1];
        const signed char* curB = sB[kt & 1];
        signed char* nA = sA[(kt + 1) & 1];
        signed char* nB = sB[(kt + 1) & 1];
        signed char* sameA = sA[kt & 1];         // kt+2 shares parity with kt
        signed char* sameB = sB[kt & 1];
        const bool pf1 = (kt + 1) < KT, pf2 = (kt + 2) < KT;

        // P1: Q(Ah0,Bh0)
        G1_PHASE(0, 0, if (pf1) stage128(A, m0, kt + 1, nA, 1, tid), )
        // P2: Q(Ah0,Bh1)
        G1_PHASE(0, 1, if (pf1) stage128(Bw, n0, kt + 1, nB, 0, tid), )
        // P3: Q(Ah1,Bh1)
        G1_PHASE(1, 1, if (pf2) stage128(A, m0, kt + 2, sameA, 0, tid), )
        // P4: Q(Ah1,Bh0) + counted vmcnt ensuring kt+1 fully resident
        G1_PHASE(1, 0, if (pf2) stage128(Bw, n0, kt + 2, sameB, 1, tid),
                 if (pf2) { __builtin_amdgcn_s_waitcnt(0x0F74); }
                 else     { __builtin_amdgcn_s_waitcnt(0x0F70); })
    }

    const float sW = *s_ptr;
#pragma unroll
    for (int fm = 0; fm < 8; ++fm) {
        const int qm = fm >> 2, f = fm & 3;
        const int grb = m0 + qm * 128 + f * 32 + wr * 16 + quad * 4;
#pragma unroll
        for (int fn = 0; fn < 4; ++fn) {
            const int qn = fn >> 1, f2 = fn & 1;
            const int gc = n0 + qn * 128 + f2 * 64 + wc * 16 + r16;
#pragma unroll
            for (int r = 0; r < 4; ++r) {
                int gr = grb + r;
                float v = (float)acc[fm][fn][r] * sW * srow[gr];
                if (gc < DI) o_xc[(size_t)gr * DI + gc] = __float2bfloat16(v);
                else         o_z[(size_t)gr * DI + (gc - DI)] = __float2bfloat16(v);
            }
        }
    }
}

// ---------------- MFMA GEMM (bf16), depth-2 pipeline (3 LDS buffers): C = A @ B^T ----------------
// MODE 1: plain bf16 out
// MODE 2: dt -> sigmoid -> dyadic u16 decay
// MODE 3: f32 out + residual  (+ XCD row-panel affinity remap, proven: FETCH 149.6 -> 49.3 MB)
// MODE 4: f32 partial (split-K over blockIdx.z, no scale)
template <int BM, int BN, int WR, int WC, int MODE>
__global__ __launch_bounds__(256) void k_gemm(
    const __hip_bfloat16* __restrict__ A, const __hip_bfloat16* __restrict__ Bw,
    int M, int N, int K, int lda, int ldb, const float* __restrict__ s_ptr,
    float* __restrict__ o_f32, __hip_bfloat16* __restrict__ o_bf16,
    unsigned short* __restrict__ o_u16,
    const float* __restrict__ bias, const float* __restrict__ resid) {
    constexpr int BK = 32;
    constexpr int FM = BM / (WR * 16), FN = BN / (WC * 16);
    constexpr int RA = (BM * BK) / (256 * 8);
    constexpr int RB = (BN * BK) / (256 * 8);
    constexpr int KEEP = RA + RB;
    __shared__ __align__(16) short lA[3][BM * BK];
    __shared__ __align__(16) short lB[3][BN * BK];
    const int tid = threadIdx.x;
    const int lane = tid & 63, wid = tid >> 6;
    const int wm = (wid / WC) * (BM / WR);
    const int wn = (wid % WC) * (BN / WC);
    const int r16 = lane & 15, quad = lane >> 4;

    if (MODE == 4) {
        A  += (size_t)blockIdx.z * K;
        Bw += (size_t)blockIdx.z * K;
        o_f32 += (size_t)blockIdx.z * M * N;
    }

    int nx = gridDim.x;
    int bx = blockIdx.x, by = blockIdx.y;
    if (MODE == 3) {
        // panel-affinity: bid%8 keeps XCD; within an XCD iterate bx fast (8 col-blocks of the
        // same row-panel co-resident on one XCD -> A-panel L2-shared 8-way; Tout likewise).
        int bid = by * nx + bx;                 // nx == 8, ny == 64
        int r = bid & 7, t = bid >> 3;
        bx = t & 7;
        by = r + 8 * (t >> 3);
    } else if ((nx & 7) == 0 && nx >= 8) {
        int bid = by * nx + bx;
        int xcd = bid & 7, idx = bid >> 3;
        int npx = nx >> 3;
        bx = xcd * npx + (idx % npx);
        by = idx / npx;
    }
    const int m0 = by * BM, n0 = bx * BN;

    floatx4 acc[FM][FN] = {};
    const int NT = K / BK;

#pragma unroll
    for (int r = 0; r < RA; ++r) {
        int idx = r * 256 + tid;
        int row = idx >> 2, kc = (idx & 3) << 3;
        async16(&A[(size_t)(m0 + row) * lda + kc], &lA[0][idx * 8]);
    }
#pragma unroll
    for (int r = 0; r < RB; ++r) {
        int idx = r * 256 + tid;
        int row = idx >> 2, kc = (idx & 3) << 3;
        async16(&Bw[(size_t)(n0 + row) * ldb + kc], &lB[0][idx * 8]);
    }
    if (NT > 1) {
#pragma unroll
        for (int r = 0; r < RA; ++r) {
            int idx = r * 256 + tid;
            int row = idx >> 2, kc = (idx & 3) << 3;
            async16(&A[(size_t)(m0 + row) * lda + BK + kc], &lA[1][idx * 8]);
        }
#pragma unroll
        for (int r = 0; r < RB; ++r) {
            int idx = r * 256 + tid;
            int row = idx >> 2, kc = (idx & 3) << 3;
            async16(&Bw[(size_t)(n0 + row) * ldb + BK + kc], &lB[1][idx * 8]);
        }
    }

    for (int t = 0; t < NT; ++t) {
        if (t > 0) __builtin_amdgcn_s_barrier();
        if (t + 2 < NT) {
            const int k2 = (t + 2) * BK;
            const int nb = (t + 2) % 3;
#pragma unroll
            for (int r = 0; r < RA; ++r) {
                int idx = r * 256 + tid;
                int row = idx >> 2, kc = (idx & 3) << 3;
                async16(&A[(size_t)(m0 + row) * lda + k2 + kc], &lA[nb][idx * 8]);
            }
#pragma unroll
            for (int r = 0; r < RB; ++r) {
                int idx = r * 256 + tid;
                int row = idx >> 2, kc = (idx & 3) << 3;
                async16(&Bw[(size_t)(n0 + row) * ldb + k2 + kc], &lB[nb][idx * 8]);
            }
            __builtin_amdgcn_s_waitcnt(0x0F70 | (2 * KEEP));
        } else if (t + 1 < NT) {
            __builtin_amdgcn_s_waitcnt(0x0F70 | KEEP);
        } else {
            __builtin_amdgcn_s_waitcnt(0x0F70);
        }
        __builtin_amdgcn_s_barrier();

        const int cb = t % 3;
        short8 af[FM], bfv[FN];
#pragma unroll
        for (int i = 0; i < FM; ++i)
            af[i] = *reinterpret_cast<const short8*>(&lA[cb][(wm + i * 16 + r16) * BK + quad * 8]);
#pragma unroll
        for (int j = 0; j < FN; ++j)
            bfv[j] = *reinterpret_cast<const short8*>(&lB[cb][(wn + j * 16 + r16) * BK + quad * 8]);
#pragma unroll
        for (int i = 0; i < FM; ++i)
#pragma unroll
            for (int j = 0; j < FN; ++j)
                acc[i][j] = __builtin_amdgcn_mfma_f32_16x16x32_bf16(af[i], bfv[j], acc[i][j], 0, 0, 0);
    }

    const float s = (MODE == 4) ? 1.0f : *s_ptr;
#pragma unroll
    for (int i = 0; i < FM; ++i) {
#pragma unroll
        for (int j = 0; j < FN; ++j) {
#pragma unroll
            for (int r = 0; r < 4; ++r) {
                int gr = m0 + wm + i * 16 + quad * 4 + r;
                int gc = n0 + wn + j * 16 + r16;
                float v = acc[i][j][r] * s;
                if (MODE == 1) {
                    o_bf16[(size_t)gr * N + gc] = __float2bfloat16(v);
                } else if (MODE == 2) {
                    float dt = v + bias[gc];
                    float dc = 0.5f + 0.5f * dt / (1.0f + fabsf(dt));
                    o_u16[(size_t)gr * N + gc] = (unsigned short)rintf(dc * 32768.0f);
                } else if (MODE == 3) {
                    o_f32[(size_t)gr * N + gc] = v + resid[(size_t)gr * N + gc];
                } else {
                    o_f32[(size_t)gr * N + gc] = v;
                }
            }
        }
    }
}

// ---------------- split-K reduce for GEMM2: dbl = bf16(s * sum_z part[z]) — float4 ----------------
__global__ __launch_bounds__(256) void k_red(const float* __restrict__ part,
                                             const float* __restrict__ s_ptr,
                                             __hip_bfloat16* __restrict__ dbl) {
    int i4 = (blockIdx.x * 256 + threadIdx.x) * 4;  // < NR*DTR
    float s = *s_ptr;
    float4 acc = make_float4(0.f, 0.f, 0.f, 0.f);
#pragma unroll
    for (int z = 0; z < KSLICE; ++z) {
        float4 p = *(const float4*)(part + (size_t)z * NR * DTR + i4);
        acc.x += p.x; acc.y += p.y; acc.z += p.z; acc.w += p.w;
    }
    ushort4v o;
    o[0] = f2bf(acc.x * s); o[1] = f2bf(acc.y * s);
    o[2] = f2bf(acc.z * s); o[3] = f2bf(acc.w * s);
    *(ushort4v*)((unsigned short*)dbl + i4) = o;
}

// ---------------- causal depthwise conv (k=4) + bias + squareplus — 4-channel vectorized ----------
// G13: scalar bf16 loads are 2-2.5x slower; each thread owns 4 consecutive channels, all
// loads/stores ushort4 (8 B/lane). CCONV=16 -> grid (2,128,4)=1024 blocks (4/CU, BW-saturating).
__global__ __launch_bounds__(256) void k_conv(const __hip_bfloat16* __restrict__ xc,
                                              const float* __restrict__ cw,
                                              const float* __restrict__ cb,
                                              __hip_bfloat16* __restrict__ xact) {
    const int c4 = (blockIdx.x * 256 + threadIdx.x) * 4;   // gridDim.x = DI/1024 = 2
    const int t0 = blockIdx.y * CCONV;
    const int b = blockIdx.z;
    float w0[4], w1[4], w2[4], w3[4], bi[4];
#pragma unroll
    for (int j = 0; j < 4; ++j) {
        float4 wv = *(const float4*)(cw + (size_t)(c4 + j) * 4);
        w0[j] = wv.x; w1[j] = wv.y; w2[j] = wv.z; w3[j] = wv.w;
        bi[j] = cb[c4 + j];
    }
    const unsigned short* src = (const unsigned short*)xc + (size_t)b * L_ * DI + c4;
    unsigned short* dst = (unsigned short*)xact + (size_t)b * L_ * DI + c4;
    float x3[4] = {}, x2[4] = {}, x1[4] = {};
    if (t0 >= 3) {   // t0 is 0 or a multiple of CCONV=16
        ushort4v v3 = *(const ushort4v*)(src + (size_t)(t0 - 3) * DI);
        ushort4v v2 = *(const ushort4v*)(src + (size_t)(t0 - 2) * DI);
        ushort4v v1 = *(const ushort4v*)(src + (size_t)(t0 - 1) * DI);
#pragma unroll
        for (int j = 0; j < 4; ++j) { x3[j] = bf2f(v3[j]); x2[j] = bf2f(v2[j]); x1[j] = bf2f(v1[j]); }
    }
#pragma unroll 4
    for (int t = t0; t < t0 + CCONV; ++t) {
        ushort4v xv = *(const ushort4v*)(src + (size_t)t * DI);
        ushort4v ov;
#pragma unroll
        for (int j = 0; j < 4; ++j) {
            float xt = bf2f(xv[j]);
            float y = x3[j] * w0[j] + x2[j] * w1[j] + x1[j] * w2[j] + xt * w3[j] + bi[j];
            ov[j] = f2bf(squareplus_f(y));
            x3[j] = x2[j]; x2[j] = x1[j]; x1[j] = xt;
        }
        *(ushort4v*)(dst + (size_t)t * DI) = ov;
    }
}

// ---------------- chunked linear scan: pass1 (chunk aggregates) — 4-channel vectorized ----------
__global__ __launch_bounds__(256) void k_scan1(const unsigned short* __restrict__ dk,
                                               const __hip_bfloat16* __restrict__ u,
                                               float* __restrict__ cA, float* __restrict__ cB) {
    const int c4 = (blockIdx.x * 256 + threadIdx.x) * 4;   // gridDim.x = 2
    const int j = blockIdx.y, b = blockIdx.z;
    const size_t base = ((size_t)b * L_ + (size_t)j * CHUNK) * DI + c4;
    const unsigned short* us = (const unsigned short*)u;
    float Ac[4] = {1.f, 1.f, 1.f, 1.f}, Bc[4] = {};
#pragma unroll 4
    for (int t = 0; t < CHUNK; ++t) {
        ushort4v a4 = *(const ushort4v*)(dk + base + (size_t)t * DI);
        ushort4v u4 = *(const ushort4v*)(us + base + (size_t)t * DI);
#pragma unroll
        for (int q = 0; q < 4; ++q) {
            float a = a4[q] * (1.0f / 32768.0f);
            float uv = bf2f(u4[q]);
            Bc[q] = a * Bc[q] + (1.f - a) * uv;
            Ac[q] *= a;
        }
    }
    size_t o = ((size_t)(b * NCHUNK + j)) * DI + c4;
    *(float4*)(cA + o) = make_float4(Ac[0], Ac[1], Ac[2], Ac[3]);
    *(float4*)(cB + o) = make_float4(Bc[0], Bc[1], Bc[2], Bc[3]);
}

// ---------------- pass2: prefix + final scan + y = h*sp(z) — 4-channel vectorized ----------------
__global__ __launch_bounds__(256) void k_scan3(const unsigned short* __restrict__ dk,
                                               const __hip_bfloat16* __restrict__ u,
                                               const __hip_bfloat16* __restrict__ zraw,
                                               const float* __restrict__ cA,
                                               const float* __restrict__ cB,
                                               __hip_bfloat16* __restrict__ y) {
    const int c4 = (blockIdx.x * 256 + threadIdx.x) * 4;   // gridDim.x = 2
    const int j = blockIdx.y, b = blockIdx.z;
    float h[4] = {};
    for (int jj = 0; jj < j; ++jj) {
        size_t o = ((size_t)(b * NCHUNK + jj)) * DI + c4;
        float4 a = *(const float4*)(cA + o);
        float4 bb = *(const float4*)(cB + o);
        h[0] = a.x * h[0] + bb.x;
        h[1] = a.y * h[1] + bb.y;
        h[2] = a.z * h[2] + bb.z;
        h[3] = a.w * h[3] + bb.w;
    }
    const size_t base = ((size_t)b * L_ + (size_t)j * CHUNK) * DI + c4;
    const unsigned short* us = (const unsigned short*)u;
    const unsigned short* zs = (const unsigned short*)zraw;
    unsigned short* ys = (unsigned short*)y;
#pragma unroll 2
    for (int t = 0; t < CHUNK; ++t) {
        ushort4v a4 = *(const ushort4v*)(dk + base + (size_t)t * DI);
        ushort4v u4 = *(const ushort4v*)(us + base + (size_t)t * DI);
        ushort4v z4 = *(const ushort4v*)(zs + base + (size_t)t * DI);
        ushort4v ov;
#pragma unroll
        for (int q = 0; q < 4; ++q) {
            float a = a4[q] * (1.0f / 32768.0f);
            float uv = bf2f(u4[q]);
            h[q] = a * h[q] + (1.f - a) * uv;
            float zv = squareplus_f(bf2f(z4[q]));
            ov[q] = f2bf(h[q] * zv);
        }
        *(ushort4v*)(ys + base + (size_t)t * DI) = ov;
    }
}

// ---------------- launch ----------------
extern "C" void kernel_launch(void* const* d_in, const int* in_sizes, int n_in,
                              void* d_out, int out_size, void* d_ws, size_t ws_size,
                              hipStream_t stream) {
    const float* x      = (const float*)d_in[0];
    const float* gamma  = (const float*)d_in[1];
    const float* step   = (const float*)d_in[2];
    const float* W_in   = (const float*)d_in[3];
    const float* conv_w = (const float*)d_in[4];
    const float* conv_b = (const float*)d_in[5];
    const float* W_x    = (const float*)d_in[6];
    const float* W_dt   = (const float*)d_in[7];
    const float* b_dt   = (const float*)d_in[8];
    const float* W_out  = (const float*)d_in[9];

    char* ws = (char*)d_ws;
    float*          scal = (float*)(ws + OFF_SCAL);
    float*          part = (float*)(ws + OFF_PART);
    signed char*    xn8  = (signed char*)(ws + OFF_XN);
    signed char*    Tin8 = (signed char*)(ws + OFF_TIN);
    __hip_bfloat16* Tx   = (__hip_bfloat16*)(ws + OFF_TX);
    __hip_bfloat16* Tdt  = (__hip_bfloat16*)(ws + OFF_TDT);
    __hip_bfloat16* Tout = (__hip_bfloat16*)(ws + OFF_TOUT);
    __hip_bfloat16* xcb  = (__hip_bfloat16*)(ws + OFF_XC);
    float*          p2   = (float*)(ws + OFF_P2);
    __hip_bfloat16* zraw = (__hip_bfloat16*)(ws + OFF_ZSP);
    __hip_bfloat16* xact = (__hip_bfloat16*)(ws + OFF_XACT);
    __hip_bfloat16* dbl  = (__hip_bfloat16*)(ws + OFF_DBL);
    unsigned short* dec  = (unsigned short*)(ws + OFF_DEC);
    float*          cA   = (float*)(ws + OFF_CA);
    float*          cB   = (float*)(ws + OFF_CB);
    __hip_bfloat16* yb   = (__hip_bfloat16*)(ws + OFF_Y);
    float*          srow = (float*)(ws + OFF_SROW);
    float*          out  = (float*)d_out;

    // weight scales + ternary quantization (fused, vectorized; W_in -> i8)
    k_abs_all<<<dim3(256, 4), 256, 0, stream>>>(W_in, W_x, W_dt, W_out, part);
    k_finalize<<<1, 256, 0, stream>>>(part, scal);
    k_quant_all<<<6400, 256, 0, stream>>>(W_in, W_x, W_dt, W_out, scal, Tin8, Tx, Tdt, Tout);

    // norm -> xn i8 + per-row scale
    k_norm<<<NR, 256, 0, stream>>>(x, gamma, step, xn8, srow);

    // GEMM1 (i8, 256^2 8-phase, no reg reuse): xz = (xn8 @ Tin8^T) * sW * srow -> xc, z
    k_gemm1_i8_8ph<<<dim3((2 * DI) / 256, NR / 256), 512, 0, stream>>>(
        xn8, Tin8, scal + 0, srow, xcb, zraw);

    // conv + bias + squareplus -> xact (bf16), 4-channel vectorized
    k_conv<<<dim3(DI / 1024, L_ / CCONV, B_), 256, 0, stream>>>(xcb, conv_w, conv_b, xact);

    // GEMM2 (split-K): p2[z] = xact[:, z*256:(z+1)*256] @ T_x[:64, ...]^T
    k_gemm<64, 64, 2, 2, 4><<<dim3(1, NR / 64, KSLICE), 256, 0, stream>>>(
        xact, Tx, NR, DTR, DI / KSLICE, DI, DI, nullptr, p2, nullptr, nullptr, nullptr, nullptr);
    k_red<<<(NR * DTR) / 1024, 256, 0, stream>>>(p2, scal + 1, dbl);

    // GEMM3: dt = dbl @ T_dt^T * s + b_dt -> sigmoid -> dyadic u16 decay (64x128 tiles)
    k_gemm<64, 128, 2, 2, 2><<<dim3(DI / 128, NR / 64), 256, 0, stream>>>(
        dbl, Tdt, NR, DI, DTR, DTR, DTR, scal + 2, nullptr, nullptr, dec, b_dt, nullptr);

    // scan (2 passes, 64-step chunks), 4-channel vectorized
    k_scan1<<<dim3(DI / 1024, NCHUNK, B_), 256, 0, stream>>>(dec, xact, cA, cB);
    k_scan3<<<dim3(DI / 1024, NCHUNK, B_), 256, 0, stream>>>(dec, xact, zraw, cA, cB, yb);

    // GEMM4: out = y @ T_out^T * s + residual  (128x128 2-phase + XCD panel-affinity remap)
    k_gemm<128, 128, 2, 2, 3><<<dim3(DM / 128, NR / 128), 256, 0, stream>>>(
        yb, Tout, NR, DM, DI, DI, DI, scal + 3, out, nullptr, nullptr, nullptr, x);

    (void)in_sizes; (void)n_in; (void)out_size; (void)ws_size;
}

// Round 7
// 333.262 us; speedup vs baseline: 1.0216x; 1.0216x over previous
//
#include <hip/hip_runtime.h>
#include <hip/hip_bf16.h>

#define B_ 4
#define L_ 2048
#define DM 1024
#define DI 2048
#define NR (B_ * L_)   // 8192 rows
#define DTR 64
#define NCHUNK 32
#define CHUNK 64
#define CCONV 16       // conv time-chunk (16 -> 1024 blocks, BW-saturating)
#define KSLICE 8       // split-K slices for GEMM2

typedef __attribute__((ext_vector_type(8))) short short8;
typedef __attribute__((ext_vector_type(4))) float floatx4;
typedef __attribute__((ext_vector_type(4))) int int4v;
typedef __attribute__((ext_vector_type(4))) unsigned short ushort4v;

// bf16 <-> f32 (bf16->f32 is exact widening; f32->bf16 uses RNE via __float2bfloat16)
__device__ __forceinline__ float bf2f(unsigned short u) {
    return __uint_as_float(((unsigned)u) << 16);
}
__device__ __forceinline__ unsigned short f2bf(float f) {
    __hip_bfloat16 h = __float2bfloat16(f);
    return *reinterpret_cast<unsigned short*>(&h);
}

// ---------------- workspace layout (bytes) ----------------
static constexpr size_t OFF_SCAL = 0;                                    // 4 f32 scales
static constexpr size_t OFF_PART = 256;                                  // 4*256 f32 partials
static constexpr size_t OFF_XN   = 4608;                                 // xn i8 [NR,DM] (8 MB of 16 MB region)
static constexpr size_t OFF_TIN  = OFF_XN   + (size_t)NR * DM * 2;       // T_in i8 [4096,1024] (4 MB of 8 MB region)
static constexpr size_t OFF_TX   = OFF_TIN  + (size_t)2 * DI * DM * 2;   // T_x bf16 [64,2048]
static constexpr size_t OFF_TDT  = OFF_TX   + (size_t)DTR * DI * 2;      // T_dt bf16 [2048,64]
static constexpr size_t OFF_TOUT = OFF_TDT  + (size_t)DI * DTR * 2;      // T_out bf16 [1024,2048]
static constexpr size_t OFF_XC   = OFF_TOUT + (size_t)DM * DI * 2;       // xc bf16 [NR,DI]
static constexpr size_t OFF_P2   = OFF_XC   + (size_t)NR * DI * 2;       // GEMM2 f32 partials [8,NR,64]
static constexpr size_t OFF_ZSP  = OFF_XC   + (size_t)NR * DI * 4;       // z raw bf16 [NR,DI]
static constexpr size_t OFF_XACT = OFF_ZSP  + (size_t)NR * DI * 2;       // sp(conv) bf16 [NR,DI]
static constexpr size_t OFF_DBL  = OFF_XACT + (size_t)NR * DI * 2;       // dbl bf16 [NR,64]
static constexpr size_t OFF_DEC  = OFF_DBL  + (size_t)NR * DTR * 2;      // decay u16 [NR,DI]
static constexpr size_t OFF_CA   = OFF_DEC  + (size_t)NR * DI * 2;       // chunk A f32 [B,32,DI]
static constexpr size_t OFF_CB   = OFF_CA   + (size_t)B_ * NCHUNK * DI * 4;
static constexpr size_t OFF_Y    = OFF_CB   + (size_t)B_ * NCHUNK * DI * 4; // y bf16 [NR,DI]
static constexpr size_t OFF_SROW = OFF_Y    + (size_t)NR * DI * 2;       // per-row xn scale f32 [NR]

// ---------------- async global->LDS (16B per lane, wave-uniform base rule) ----------------
__device__ __forceinline__ void async16(const void* g, void* l) {
    __builtin_amdgcn_global_load_lds(
        (const __attribute__((address_space(1))) unsigned int*)g,
        (__attribute__((address_space(3))) unsigned int*)l, 16, 0, 0);
}

// ---------------- scalar math (bit-faithful to reference) ----------------
__device__ __forceinline__ float pow2scale(float var) {
    float v = var + 1e-9f;
    float s = 1.0f;
    if (v >= 4.0f)     s = 0.5f;
    if (v >= 16.0f)    s = 0.25f;
    if (v >= 64.0f)    s = 0.125f;
    if (v >= 256.0f)   s = 0.0625f;
    if (v >= 1024.0f)  s = 0.03125f;
    if (v >= 4096.0f)  s = 0.015625f;
    if (v >= 16384.0f) s = 0.0078125f;
    if (v >= 65536.0f) s = 0.00390625f;
    if (v < 1.0f)    s = 1.0f;
    if (v < 0.25f)   s = 2.0f;
    if (v < 0.0625f) s = 4.0f;
    return s;
}

// NOTE: must stay bit-faithful — the reference's Newton rsqrt genuinely diverges
// for y=x^2+4 in (12,16] (seed 0.5, clip to 1e-6 -> sp(x)=x/2 there). Do NOT
// replace with true rsqrt.
__device__ __forceinline__ float squareplus_f(float x) {
    float y = fminf(fmaxf(x * x + 4.0f, 1e-6f), 1e6f);
    float r = (y > 16.0f) ? 0.125f : 0.5f;
    if (y > 64.0f)  r = 0.0625f;
    if (y > 256.0f) r = 0.03125f;
    if (y < 4.0f)   r = 1.0f;
    if (y < 1.0f)   r = 2.0f;
    if (y < 0.25f)  r = 4.0f;
#pragma unroll
    for (int i = 0; i < 3; ++i) {
        r = r * (1.5f - 0.5f * y * r * r);
        r = fminf(fmaxf(r, 1e-6f), 1e3f);
    }
    float s = fminf(fmaxf(y * r, 0.0f), 1e3f);
    return 0.5f * (x + s);
}

__device__ __forceinline__ float block_reduce_sum(float v) {
    __shared__ float sm[4];
#pragma unroll
    for (int o = 32; o > 0; o >>= 1) v += __shfl_down(v, o, 64);
    int w = threadIdx.x >> 6;
    __syncthreads();
    if ((threadIdx.x & 63) == 0) sm[w] = v;
    __syncthreads();
    return (sm[0] + sm[1]) + (sm[2] + sm[3]);
}

__device__ __forceinline__ float block_reduce_max(float v) {
    __shared__ float smx[4];
#pragma unroll
    for (int o = 32; o > 0; o >>= 1) v = fmaxf(v, __shfl_down(v, o, 64));
    int w = threadIdx.x >> 6;
    __syncthreads();
    if ((threadIdx.x & 63) == 0) smx[w] = v;
    __syncthreads();
    return fmaxf(fmaxf(smx[0], smx[1]), fmaxf(smx[2], smx[3]));
}

// ---------------- fused weight-scale partials (all 4 weights, one launch, float4) ----------------
__global__ __launch_bounds__(256) void k_abs_all(const float* __restrict__ W0,
                                                 const float* __restrict__ W1,
                                                 const float* __restrict__ W2,
                                                 const float* __restrict__ W3,
                                                 float* __restrict__ part) {
    const int w = blockIdx.y;
    const float* W = (w == 0) ? W0 : (w == 1) ? W1 : (w == 2) ? W2 : W3;
    const int n4 = ((w == 0) ? 2 * DI * DM : (w == 1) ? 96 * DI : (w == 2) ? DI * DTR : DM * DI) / 4;
    const float4* W4 = (const float4*)W;
    float s = 0.f;
    for (int i = blockIdx.x * 256 + threadIdx.x; i < n4; i += 256 * 256) {
        float4 v = W4[i];
        s += fabsf(v.x) + fabsf(v.y) + fabsf(v.z) + fabsf(v.w);
    }
    float t = block_reduce_sum(s);
    if (threadIdx.x == 0) part[w * 256 + blockIdx.x] = t;
}

__global__ __launch_bounds__(256) void k_finalize(const float* __restrict__ part,
                                                  float* __restrict__ scal) {
    const float counts[4] = {(float)(2 * DI * DM), (float)(96 * DI),
                             (float)(DI * DTR), (float)(DM * DI)};
    for (int w = 0; w < 4; ++w) {
        float s = block_reduce_sum(part[w * 256 + threadIdx.x]);
        if (threadIdx.x == 0) scal[w] = s / counts[w] + 1e-8f;
    }
}

// ---------------- fused ternary quantization ----------------
// W_in -> i8 (exact ternary); W_x/W_dt/W_out -> bf16 (exact ternary)
// block segments (1024 elems/block): W_in 4096 | W_x[:64] 128 | W_dt 128 | W_out 2048 = 6400
__global__ __launch_bounds__(256) void k_quant_all(
    const float* __restrict__ W0, const float* __restrict__ W1,
    const float* __restrict__ W2, const float* __restrict__ W3,
    const float* __restrict__ scal,
    signed char* __restrict__ T0, __hip_bfloat16* __restrict__ T1,
    __hip_bfloat16* __restrict__ T2, __hip_bfloat16* __restrict__ T3) {
    int b = blockIdx.x;
    if (b < 4096) {
        int i = b * 1024 + threadIdx.x * 4;
        float inv = 1.0f / scal[0];
        float4 v = *(const float4*)(W0 + i);
        int q0 = (int)fmaxf(-1.0f, fminf(1.0f, rintf(v.x * inv)));
        int q1 = (int)fmaxf(-1.0f, fminf(1.0f, rintf(v.y * inv)));
        int q2 = (int)fmaxf(-1.0f, fminf(1.0f, rintf(v.z * inv)));
        int q3 = (int)fmaxf(-1.0f, fminf(1.0f, rintf(v.w * inv)));
        unsigned int packed = (q0 & 255) | ((q1 & 255) << 8) | ((q2 & 255) << 16) | ((q3 & 255) << 24);
        *reinterpret_cast<unsigned int*>(&T0[i]) = packed;
        return;
    }
    const float* W; const float* sp; __hip_bfloat16* T; int off;
    if (b < 4224)      { W = W1; sp = scal + 1; T = T1; off = b - 4096; }
    else if (b < 4352) { W = W2; sp = scal + 2; T = T2; off = b - 4224; }
    else               { W = W3; sp = scal + 3; T = T3; off = b - 4352; }
    int i = off * 1024 + threadIdx.x * 4;
    float inv = 1.0f / (*sp);
    float4 v = *(const float4*)(W + i);
    __hip_bfloat16 t[4];
    t[0] = __float2bfloat16(fmaxf(-1.0f, fminf(1.0f, rintf(v.x * inv))));
    t[1] = __float2bfloat16(fmaxf(-1.0f, fminf(1.0f, rintf(v.y * inv))));
    t[2] = __float2bfloat16(fmaxf(-1.0f, fminf(1.0f, rintf(v.z * inv))));
    t[3] = __float2bfloat16(fmaxf(-1.0f, fminf(1.0f, rintf(v.w * inv))));
    *reinterpret_cast<uint2*>(&T[i]) = *reinterpret_cast<uint2*>(t);
}

// ---------------- bitshift_norm -> per-row i8 quantized xn + row scale ----------------
__global__ __launch_bounds__(256) void k_norm(const float* __restrict__ x,
                                              const float* __restrict__ gamma,
                                              const float* __restrict__ step,
                                              signed char* __restrict__ xn8,
                                              float* __restrict__ srow) {
    int row = blockIdx.x;
    int tid = threadIdx.x;
    float4 v4 = ((const float4*)(x + (size_t)row * DM))[tid];
    float s = (v4.x + v4.y) + (v4.z + v4.w);
    float mean = block_reduce_sum(s) * (1.0f / DM);
    float d0 = v4.x - mean, d1 = v4.y - mean, d2 = v4.z - mean, d3 = v4.w - mean;
    float vv = d0 * d0 + d1 * d1 + d2 * d2 + d3 * d3;
    float var = block_reduce_sum(vv) * (1.0f / DM);
    float sc = pow2scale(var) * step[0];
    float4 g = ((const float4*)gamma)[tid];
    float w0 = d0 * sc * g.x, w1 = d1 * sc * g.y, w2 = d2 * sc * g.z, w3 = d3 * sc * g.w;
    float am = fmaxf(fmaxf(fabsf(w0), fabsf(w1)), fmaxf(fabsf(w2), fabsf(w3)));
    am = block_reduce_max(am);
    float sr = (am > 0.f) ? am * (1.0f / 127.0f) : 1.0f;
    float inv = 1.0f / sr;
    if (tid == 0) srow[row] = sr;
    int q0 = (int)rintf(w0 * inv), q1 = (int)rintf(w1 * inv);
    int q2 = (int)rintf(w2 * inv), q3 = (int)rintf(w3 * inv);
    unsigned int packed = (q0 & 255) | ((q1 & 255) << 8) | ((q2 & 255) << 16) | ((q3 & 255) << 24);
    ((unsigned int*)xn8)[row * 256 + tid] = packed;
}

// ---------------- GEMM1 (i8): 256x256 tile, 8-phase schedule + MINIMAL cross-phase reg reuse ----
// LDS-read-bound analysis: 48 b128/K-tile/wave ~= 31 us of the 64 us. Reuse plan (vs R3's failed
// full-reuse: every phase here keeps >=4 ds_reads, only one 12-read phase, one B set):
//   P1: read af=Ah0(8)+bf=Bh0(4) -> Q(0,0);  P2: read bf=Bh1(4), af held -> Q(0,1)
//   P3: read af=Ah1(8), bf held  -> Q(1,1);  P4: read bf=Bh0(4), af held -> Q(1,0)
// = 28 reads/K-tile (-42%). Hazard ledger unchanged: curB.h0 last staged at P2 of kt-1, never
// touched during kt (P4 stages (kt+2).Bh1 into half1) -> P4's re-read valid. Stage slots per kt:
// P1:(kt+1).Ah1  P2:(kt+1).Bh0  P3:(kt+2).Ah0  P4:(kt+2).Bh1 + vmcnt(4).
__device__ __forceinline__ void stage128(const signed char* __restrict__ G, int base0,
                                         int ktile, signed char* lds, int half, int tid) {
#pragma unroll
    for (int r = 0; r < 2; ++r) {
        int slot = r * 512 + tid;
        int rih = slot >> 3, sl = slot & 7;
        async16(&G[(size_t)(base0 + half * 128 + rih) * DM + (size_t)ktile * 128 + ((sl ^ (rih & 7)) << 4)],
                &lds[half * 16384 + slot * 16]);
    }
}

#define G1_READ_A(HALF)                                                              \
    _Pragma("unroll") for (int f = 0; f < 4; ++f) {                                  \
        int rb = (HALF) * 128 + f * 32 + wr * 16 + r16;                              \
        _Pragma("unroll") for (int kc = 0; kc < 2; ++kc)                             \
            af[f][kc] = *reinterpret_cast<const int4v*>(                             \
                &curA[rb * 128 + (((kc * 4 + quad) ^ (rb & 7)) << 4)]);              \
    }

#define G1_READ_B(HALF)                                                              \
    _Pragma("unroll") for (int f = 0; f < 2; ++f) {                                  \
        int cb = (HALF) * 128 + f * 64 + wc * 16 + r16;                              \
        _Pragma("unroll") for (int kc = 0; kc < 2; ++kc)                             \
            bf[f][kc] = *reinterpret_cast<const int4v*>(                             \
                &curB[cb * 128 + (((kc * 4 + quad) ^ (cb & 7)) << 4)]);              \
    }

#define G1_MFMA_BLOCK(QM, QN, STAGE, LASTOP)                                         \
    {                                                                                \
        STAGE;                                                                       \
        __builtin_amdgcn_s_barrier();                                                \
        __builtin_amdgcn_s_setprio(1);                                               \
        _Pragma("unroll") for (int f = 0; f < 4; ++f)                                \
        _Pragma("unroll") for (int g = 0; g < 2; ++g)                                \
        _Pragma("unroll") for (int kc = 0; kc < 2; ++kc)                             \
            acc[(QM) * 4 + f][(QN) * 2 + g] = __builtin_amdgcn_mfma_i32_16x16x64_i8( \
                af[f][kc], bf[g][kc], acc[(QM) * 4 + f][(QN) * 2 + g], 0, 0, 0);     \
        __builtin_amdgcn_s_setprio(0);                                               \
        LASTOP;                                                                      \
        __builtin_amdgcn_s_barrier();                                                \
    }

__global__ __launch_bounds__(512) void k_gemm1_i8_8ph(
    const signed char* __restrict__ A, const signed char* __restrict__ Bw,
    const float* __restrict__ s_ptr, const float* __restrict__ srow,
    __hip_bfloat16* __restrict__ o_xc, __hip_bfloat16* __restrict__ o_z) {
    __shared__ __align__(16) signed char sA[2][32768];  // [dbuf][half*16384 + row*128 + slot*16]
    __shared__ __align__(16) signed char sB[2][32768];
    const int tid = threadIdx.x;
    const int lane = tid & 63, wid = tid >> 6;
    const int wr = wid >> 2, wc = wid & 3;      // 2 x 4 waves
    const int r16 = lane & 15, quad = lane >> 4;

    int nx = gridDim.x;                          // 16
    int bx = blockIdx.x, by = blockIdx.y;
    {
        int bid = by * nx + bx;
        int xcd = bid & 7, idx = bid >> 3;
        int npx = nx >> 3;                       // 2
        bx = xcd * npx + (idx % npx);
        by = idx / npx;
    }
    const int m0 = by * 256, n0 = bx * 256;

    int4v acc[8][4] = {};
    constexpr int KT = DM / 128;                 // 8 K-tiles

    // prologue: kt0 {Ah0,Bh1,Ah1,Bh0} + kt1 {Ah0,Bh1}  (12 loads); wait oldest 8 (= all of kt0)
    stage128(A,  m0, 0, sA[0], 0, tid);
    stage128(Bw, n0, 0, sB[0], 1, tid);
    stage128(A,  m0, 0, sA[0], 1, tid);
    stage128(Bw, n0, 0, sB[0], 0, tid);
    stage128(A,  m0, 1, sA[1], 0, tid);
    stage128(Bw, n0, 1, sB[1], 1, tid);
    __builtin_amdgcn_s_waitcnt(0x0F74);          // vmcnt(4)
    __builtin_amdgcn_s_barrier();

    for (int kt = 0; kt < KT; ++kt) {
        const signed char* curA = sA[kt & 1];
        const signed char* curB = sB[kt & 1];
        signed char* nA = sA[(kt + 1) & 1];
        signed char* nB = sB[(kt + 1) & 1];
        signed char* sameA = sA[kt & 1];         // kt+2 shares parity with kt
        signed char* sameB = sB[kt & 1];
        const bool pf1 = (kt + 1) < KT, pf2 = (kt + 2) < KT;

        int4v af[4][2], bf[2][2];

        // P1: Q(Ah0,Bh0) — read af (8) + bf (4)
        G1_READ_A(0)
        G1_READ_B(0)
        G1_MFMA_BLOCK(0, 0, if (pf1) stage128(A, m0, kt + 1, nA, 1, tid), )
        // P2: Q(Ah0,Bh1) — read bf=Bh1 (4), af held
        G1_READ_B(1)
        G1_MFMA_BLOCK(0, 1, if (pf1) stage128(Bw, n0, kt + 1, nB, 0, tid), )
        // P3: Q(Ah1,Bh1) — read af=Ah1 (8), bf held
        G1_READ_A(1)
        G1_MFMA_BLOCK(1, 1, if (pf2) stage128(A, m0, kt + 2, sameA, 0, tid), )
        // P4: Q(Ah1,Bh0) — read bf=Bh0 (4), af held; counted vmcnt
        G1_READ_B(0)
        G1_MFMA_BLOCK(1, 0, if (pf2) stage128(Bw, n0, kt + 2, sameB, 1, tid),
                 if (pf2) { __builtin_amdgcn_s_waitcnt(0x0F74); }
                 else     { __builtin_amdgcn_s_waitcnt(0x0F70); })
    }

    const float sW = *s_ptr;
#pragma unroll
    for (int fm = 0; fm < 8; ++fm) {
        const int qm = fm >> 2, f = fm & 3;
        const int grb = m0 + qm * 128 + f * 32 + wr * 16 + quad * 4;
#pragma unroll
        for (int fn = 0; fn < 4; ++fn) {
            const int qn = fn >> 1, f2 = fn & 1;
            const int gc = n0 + qn * 128 + f2 * 64 + wc * 16 + r16;
#pragma unroll
            for (int r = 0; r < 4; ++r) {
                int gr = grb + r;
                float v = (float)acc[fm][fn][r] * sW * srow[gr];
                if (gc < DI) o_xc[(size_t)gr * DI + gc] = __float2bfloat16(v);
                else         o_z[(size_t)gr * DI + (gc - DI)] = __float2bfloat16(v);
            }
        }
    }
}

// ---------------- MFMA GEMM (bf16), depth-2 pipeline (3 LDS buffers): C = A @ B^T ----------------
// MODE 1: plain bf16 out
// MODE 2: dt -> sigmoid -> dyadic u16 decay + FUSED scan1: the BM=64 row-tile is exactly one
//         (batch, chunk) of 64 timesteps; epilogue stashes dec in LDS (reuses dead lB), then
//         128 column-threads scan 64 steps reading u_in (xact) coalesced -> cA/cB. Eliminates
//         the k_scan1 kernel and its 67 MB re-read of dec+xact.
// MODE 3: f32 out + residual  (+ XCD row-panel affinity remap, proven: FETCH 149.6 -> 49.3 MB)
// MODE 4: f32 partial (split-K over blockIdx.z, no scale)
template <int BM, int BN, int WR, int WC, int MODE>
__global__ __launch_bounds__(256) void k_gemm(
    const __hip_bfloat16* __restrict__ A, const __hip_bfloat16* __restrict__ Bw,
    int M, int N, int K, int lda, int ldb, const float* __restrict__ s_ptr,
    float* __restrict__ o_f32, __hip_bfloat16* __restrict__ o_bf16,
    unsigned short* __restrict__ o_u16,
    const float* __restrict__ bias, const float* __restrict__ resid,
    const __hip_bfloat16* __restrict__ u_in, float* __restrict__ cA,
    float* __restrict__ cB) {
    constexpr int BK = 32;
    constexpr int FM = BM / (WR * 16), FN = BN / (WC * 16);
    constexpr int RA = (BM * BK) / (256 * 8);
    constexpr int RB = (BN * BK) / (256 * 8);
    constexpr int KEEP = RA + RB;
    __shared__ __align__(16) short lA[3][BM * BK];
    __shared__ __align__(16) short lB[3][BN * BK];
    const int tid = threadIdx.x;
    const int lane = tid & 63, wid = tid >> 6;
    const int wm = (wid / WC) * (BM / WR);
    const int wn = (wid % WC) * (BN / WC);
    const int r16 = lane & 15, quad = lane >> 4;

    if (MODE == 4) {
        A  += (size_t)blockIdx.z * K;
        Bw += (size_t)blockIdx.z * K;
        o_f32 += (size_t)blockIdx.z * M * N;
    }

    int nx = gridDim.x;
    int bx = blockIdx.x, by = blockIdx.y;
    if (MODE == 3) {
        // panel-affinity: bid%8 keeps XCD; within an XCD iterate bx fast (8 col-blocks of the
        // same row-panel co-resident on one XCD -> A-panel L2-shared 8-way; Tout likewise).
        int bid = by * nx + bx;                 // nx == 8, ny == 64
        int r = bid & 7, t = bid >> 3;
        bx = t & 7;
        by = r + 8 * (t >> 3);
    } else if ((nx & 7) == 0 && nx >= 8) {
        int bid = by * nx + bx;
        int xcd = bid & 7, idx = bid >> 3;
        int npx = nx >> 3;
        bx = xcd * npx + (idx % npx);
        by = idx / npx;
    }
    const int m0 = by * BM, n0 = bx * BN;

    floatx4 acc[FM][FN] = {};
    const int NT = K / BK;

#pragma unroll
    for (int r = 0; r < RA; ++r) {
        int idx = r * 256 + tid;
        int row = idx >> 2, kc = (idx & 3) << 3;
        async16(&A[(size_t)(m0 + row) * lda + kc], &lA[0][idx * 8]);
    }
#pragma unroll
    for (int r = 0; r < RB; ++r) {
        int idx = r * 256 + tid;
        int row = idx >> 2, kc = (idx & 3) << 3;
        async16(&Bw[(size_t)(n0 + row) * ldb + kc], &lB[0][idx * 8]);
    }
    if (NT > 1) {
#pragma unroll
        for (int r = 0; r < RA; ++r) {
            int idx = r * 256 + tid;
            int row = idx >> 2, kc = (idx & 3) << 3;
            async16(&A[(size_t)(m0 + row) * lda + BK + kc], &lA[1][idx * 8]);
        }
#pragma unroll
        for (int r = 0; r < RB; ++r) {
            int idx = r * 256 + tid;
            int row = idx >> 2, kc = (idx & 3) << 3;
            async16(&Bw[(size_t)(n0 + row) * ldb + BK + kc], &lB[1][idx * 8]);
        }
    }

    for (int t = 0; t < NT; ++t) {
        if (t > 0) __builtin_amdgcn_s_barrier();
        if (t + 2 < NT) {
            const int k2 = (t + 2) * BK;
            const int nb = (t + 2) % 3;
#pragma unroll
            for (int r = 0; r < RA; ++r) {
                int idx = r * 256 + tid;
                int row = idx >> 2, kc = (idx & 3) << 3;
                async16(&A[(size_t)(m0 + row) * lda + k2 + kc], &lA[nb][idx * 8]);
            }
#pragma unroll
            for (int r = 0; r < RB; ++r) {
                int idx = r * 256 + tid;
                int row = idx >> 2, kc = (idx & 3) << 3;
                async16(&Bw[(size_t)(n0 + row) * ldb + k2 + kc], &lB[nb][idx * 8]);
            }
            __builtin_amdgcn_s_waitcnt(0x0F70 | (2 * KEEP));
        } else if (t + 1 < NT) {
            __builtin_amdgcn_s_waitcnt(0x0F70 | KEEP);
        } else {
            __builtin_amdgcn_s_waitcnt(0x0F70);
        }
        __builtin_amdgcn_s_barrier();

        const int cb = t % 3;
        short8 af[FM], bfv[FN];
#pragma unroll
        for (int i = 0; i < FM; ++i)
            af[i] = *reinterpret_cast<const short8*>(&lA[cb][(wm + i * 16 + r16) * BK + quad * 8]);
#pragma unroll
        for (int j = 0; j < FN; ++j)
            bfv[j] = *reinterpret_cast<const short8*>(&lB[cb][(wn + j * 16 + r16) * BK + quad * 8]);
#pragma unroll
        for (int i = 0; i < FM; ++i)
#pragma unroll
            for (int j = 0; j < FN; ++j)
                acc[i][j] = __builtin_amdgcn_mfma_f32_16x16x32_bf16(af[i], bfv[j], acc[i][j], 0, 0, 0);
    }

    const float s = (MODE == 4) ? 1.0f : *s_ptr;
    if (MODE == 2) {
        // dec epilogue + fused scan1
        unsigned short dv[FM][FN][4];
#pragma unroll
        for (int i = 0; i < FM; ++i) {
#pragma unroll
            for (int j = 0; j < FN; ++j) {
#pragma unroll
                for (int r = 0; r < 4; ++r) {
                    int gr = m0 + wm + i * 16 + quad * 4 + r;
                    int gc = n0 + wn + j * 16 + r16;
                    float dt = acc[i][j][r] * s + bias[gc];
                    float dc = 0.5f + 0.5f * dt / (1.0f + fabsf(dt));
                    unsigned short q = (unsigned short)rintf(dc * 32768.0f);
                    o_u16[(size_t)gr * N + gc] = q;
                    dv[i][j][r] = q;
                }
            }
        }
        __syncthreads();   // all waves done reading lB (K-loop) before overwrite
        unsigned short* sdec = reinterpret_cast<unsigned short*>(&lB[0][0]);  // 16 KB of 24 KB
#pragma unroll
        for (int i = 0; i < FM; ++i)
#pragma unroll
            for (int j = 0; j < FN; ++j)
#pragma unroll
                for (int r = 0; r < 4; ++r) {
                    int lr = wm + i * 16 + quad * 4 + r;
                    int lc = wn + j * 16 + r16;
                    sdec[lr * BN + lc] = dv[i][j][r];
                }
        __syncthreads();
        if (tid < BN) {    // 128 column-threads scan the 64 timesteps of this (b, chunk)
            const int lc = tid;
            const unsigned short* us = (const unsigned short*)u_in + (size_t)m0 * DI + n0 + lc;
            float Ac = 1.f, Bc = 0.f;
            for (int t = 0; t < BM; ++t) {
                float a = sdec[t * BN + lc] * (1.0f / 32768.0f);
                float uv = bf2f(us[(size_t)t * DI]);
                Bc = a * Bc + (1.f - a) * uv;
                Ac *= a;
            }
            int bb = m0 >> 11;           // / L_
            int jj = (m0 & 2047) >> 6;   // chunk within batch
            size_t o = ((size_t)(bb * NCHUNK + jj)) * DI + n0 + lc;
            cA[o] = Ac;
            cB[o] = Bc;
        }
        return;
    }
#pragma unroll
    for (int i = 0; i < FM; ++i) {
#pragma unroll
        for (int j = 0; j < FN; ++j) {
#pragma unroll
            for (int r = 0; r < 4; ++r) {
                int gr = m0 + wm + i * 16 + quad * 4 + r;
                int gc = n0 + wn + j * 16 + r16;
                float v = acc[i][j][r] * s;
                if (MODE == 1) {
                    o_bf16[(size_t)gr * N + gc] = __float2bfloat16(v);
                } else if (MODE == 3) {
                    o_f32[(size_t)gr * N + gc] = v + resid[(size_t)gr * N + gc];
                } else {
                    o_f32[(size_t)gr * N + gc] = v;
                }
            }
        }
    }
}

// ---------------- split-K reduce for GEMM2: dbl = bf16(s * sum_z part[z]) — float4 ----------------
__global__ __launch_bounds__(256) void k_red(const float* __restrict__ part,
                                             const float* __restrict__ s_ptr,
                                             __hip_bfloat16* __restrict__ dbl) {
    int i4 = (blockIdx.x * 256 + threadIdx.x) * 4;  // < NR*DTR
    float s = *s_ptr;
    float4 acc = make_float4(0.f, 0.f, 0.f, 0.f);
#pragma unroll
    for (int z = 0; z < KSLICE; ++z) {
        float4 p = *(const float4*)(part + (size_t)z * NR * DTR + i4);
        acc.x += p.x; acc.y += p.y; acc.z += p.z; acc.w += p.w;
    }
    ushort4v o;
    o[0] = f2bf(acc.x * s); o[1] = f2bf(acc.y * s);
    o[2] = f2bf(acc.z * s); o[3] = f2bf(acc.w * s);
    *(ushort4v*)((unsigned short*)dbl + i4) = o;
}

// ---------------- causal depthwise conv (k=4) + bias + squareplus — 4-channel vectorized ----------
__global__ __launch_bounds__(256) void k_conv(const __hip_bfloat16* __restrict__ xc,
                                              const float* __restrict__ cw,
                                              const float* __restrict__ cb,
                                              __hip_bfloat16* __restrict__ xact) {
    const int c4 = (blockIdx.x * 256 + threadIdx.x) * 4;   // gridDim.x = DI/1024 = 2
    const int t0 = blockIdx.y * CCONV;
    const int b = blockIdx.z;
    float w0[4], w1[4], w2[4], w3[4], bi[4];
#pragma unroll
    for (int j = 0; j < 4; ++j) {
        float4 wv = *(const float4*)(cw + (size_t)(c4 + j) * 4);
        w0[j] = wv.x; w1[j] = wv.y; w2[j] = wv.z; w3[j] = wv.w;
        bi[j] = cb[c4 + j];
    }
    const unsigned short* src = (const unsigned short*)xc + (size_t)b * L_ * DI + c4;
    unsigned short* dst = (unsigned short*)xact + (size_t)b * L_ * DI + c4;
    float x3[4] = {}, x2[4] = {}, x1[4] = {};
    if (t0 >= 3) {   // t0 is 0 or a multiple of CCONV=16
        ushort4v v3 = *(const ushort4v*)(src + (size_t)(t0 - 3) * DI);
        ushort4v v2 = *(const ushort4v*)(src + (size_t)(t0 - 2) * DI);
        ushort4v v1 = *(const ushort4v*)(src + (size_t)(t0 - 1) * DI);
#pragma unroll
        for (int j = 0; j < 4; ++j) { x3[j] = bf2f(v3[j]); x2[j] = bf2f(v2[j]); x1[j] = bf2f(v1[j]); }
    }
#pragma unroll 4
    for (int t = t0; t < t0 + CCONV; ++t) {
        ushort4v xv = *(const ushort4v*)(src + (size_t)t * DI);
        ushort4v ov;
#pragma unroll
        for (int j = 0; j < 4; ++j) {
            float xt = bf2f(xv[j]);
            float y = x3[j] * w0[j] + x2[j] * w1[j] + x1[j] * w2[j] + xt * w3[j] + bi[j];
            ov[j] = f2bf(squareplus_f(y));
            x3[j] = x2[j]; x2[j] = x1[j]; x1[j] = xt;
        }
        *(ushort4v*)(dst + (size_t)t * DI) = ov;
    }
}

// ---------------- pass2: prefix + final scan + y = h*sp(z) — 4-channel vectorized ----------------
__global__ __launch_bounds__(256) void k_scan3(const unsigned short* __restrict__ dk,
                                               const __hip_bfloat16* __restrict__ u,
                                               const __hip_bfloat16* __restrict__ zraw,
                                               const float* __restrict__ cA,
                                               const float* __restrict__ cB,
                                               __hip_bfloat16* __restrict__ y) {
    const int c4 = (blockIdx.x * 256 + threadIdx.x) * 4;   // gridDim.x = 2
    const int j = blockIdx.y, b = blockIdx.z;
    float h[4] = {};
    for (int jj = 0; jj < j; ++jj) {
        size_t o = ((size_t)(b * NCHUNK + jj)) * DI + c4;
        float4 a = *(const float4*)(cA + o);
        float4 bb = *(const float4*)(cB + o);
        h[0] = a.x * h[0] + bb.x;
        h[1] = a.y * h[1] + bb.y;
        h[2] = a.z * h[2] + bb.z;
        h[3] = a.w * h[3] + bb.w;
    }
    const size_t base = ((size_t)b * L_ + (size_t)j * CHUNK) * DI + c4;
    const unsigned short* us = (const unsigned short*)u;
    const unsigned short* zs = (const unsigned short*)zraw;
    unsigned short* ys = (unsigned short*)y;
#pragma unroll 2
    for (int t = 0; t < CHUNK; ++t) {
        ushort4v a4 = *(const ushort4v*)(dk + base + (size_t)t * DI);
        ushort4v u4 = *(const ushort4v*)(us + base + (size_t)t * DI);
        ushort4v z4 = *(const ushort4v*)(zs + base + (size_t)t * DI);
        ushort4v ov;
#pragma unroll
        for (int q = 0; q < 4; ++q) {
            float a = a4[q] * (1.0f / 32768.0f);
            float uv = bf2f(u4[q]);
            h[q] = a * h[q] + (1.f - a) * uv;
            float zv = squareplus_f(bf2f(z4[q]));
            ov[q] = f2bf(h[q] * zv);
        }
        *(ushort4v*)(ys + base + (size_t)t * DI) = ov;
    }
}

// ---------------- launch ----------------
extern "C" void kernel_launch(void* const* d_in, const int* in_sizes, int n_in,
                              void* d_out, int out_size, void* d_ws, size_t ws_size,
                              hipStream_t stream) {
    const float* x      = (const float*)d_in[0];
    const float* gamma  = (const float*)d_in[1];
    const float* step   = (const float*)d_in[2];
    const float* W_in   = (const float*)d_in[3];
    const float* conv_w = (const float*)d_in[4];
    const float* conv_b = (const float*)d_in[5];
    const float* W_x    = (const float*)d_in[6];
    const float* W_dt   = (const float*)d_in[7];
    const float* b_dt   = (const float*)d_in[8];
    const float* W_out  = (const float*)d_in[9];

    char* ws = (char*)d_ws;
    float*          scal = (float*)(ws + OFF_SCAL);
    float*          part = (float*)(ws + OFF_PART);
    signed char*    xn8  = (signed char*)(ws + OFF_XN);
    signed char*    Tin8 = (signed char*)(ws + OFF_TIN);
    __hip_bfloat16* Tx   = (__hip_bfloat16*)(ws + OFF_TX);
    __hip_bfloat16* Tdt  = (__hip_bfloat16*)(ws + OFF_TDT);
    __hip_bfloat16* Tout = (__hip_bfloat16*)(ws + OFF_TOUT);
    __hip_bfloat16* xcb  = (__hip_bfloat16*)(ws + OFF_XC);
    float*          p2   = (float*)(ws + OFF_P2);
    __hip_bfloat16* zraw = (__hip_bfloat16*)(ws + OFF_ZSP);
    __hip_bfloat16* xact = (__hip_bfloat16*)(ws + OFF_XACT);
    __hip_bfloat16* dbl  = (__hip_bfloat16*)(ws + OFF_DBL);
    unsigned short* dec  = (unsigned short*)(ws + OFF_DEC);
    float*          cA   = (float*)(ws + OFF_CA);
    float*          cB   = (float*)(ws + OFF_CB);
    __hip_bfloat16* yb   = (__hip_bfloat16*)(ws + OFF_Y);
    float*          srow = (float*)(ws + OFF_SROW);
    float*          out  = (float*)d_out;

    // weight scales + ternary quantization (fused, vectorized; W_in -> i8)
    k_abs_all<<<dim3(256, 4), 256, 0, stream>>>(W_in, W_x, W_dt, W_out, part);
    k_finalize<<<1, 256, 0, stream>>>(part, scal);
    k_quant_all<<<6400, 256, 0, stream>>>(W_in, W_x, W_dt, W_out, scal, Tin8, Tx, Tdt, Tout);

    // norm -> xn i8 + per-row scale
    k_norm<<<NR, 256, 0, stream>>>(x, gamma, step, xn8, srow);

    // GEMM1 (i8, 256^2 8-phase + minimal reg reuse): xz = (xn8 @ Tin8^T) * sW * srow -> xc, z
    k_gemm1_i8_8ph<<<dim3((2 * DI) / 256, NR / 256), 512, 0, stream>>>(
        xn8, Tin8, scal + 0, srow, xcb, zraw);

    // conv + bias + squareplus -> xact (bf16), 4-channel vectorized
    k_conv<<<dim3(DI / 1024, L_ / CCONV, B_), 256, 0, stream>>>(xcb, conv_w, conv_b, xact);

    // GEMM2 (split-K): p2[z] = xact[:, z*256:(z+1)*256] @ T_x[:64, ...]^T
    k_gemm<64, 64, 2, 2, 4><<<dim3(1, NR / 64, KSLICE), 256, 0, stream>>>(
        xact, Tx, NR, DTR, DI / KSLICE, DI, DI, nullptr, p2, nullptr, nullptr, nullptr, nullptr,
        nullptr, nullptr, nullptr);
    k_red<<<(NR * DTR) / 1024, 256, 0, stream>>>(p2, scal + 1, dbl);

    // GEMM3: dt = dbl @ T_dt^T * s + b_dt -> sigmoid -> dyadic u16 decay, + FUSED scan1
    k_gemm<64, 128, 2, 2, 2><<<dim3(DI / 128, NR / 64), 256, 0, stream>>>(
        dbl, Tdt, NR, DI, DTR, DTR, DTR, scal + 2, nullptr, nullptr, dec, b_dt, nullptr,
        xact, cA, cB);

    // scan pass2 (prefix from fused chunk aggregates) + y = h * squareplus(z)
    k_scan3<<<dim3(DI / 1024, NCHUNK, B_), 256, 0, stream>>>(dec, xact, zraw, cA, cB, yb);

    // GEMM4: out = y @ T_out^T * s + residual  (128x128 2-phase + XCD panel-affinity remap)
    k_gemm<128, 128, 2, 2, 3><<<dim3(DM / 128, NR / 128), 256, 0, stream>>>(
        yb, Tout, NR, DM, DI, DI, DI, scal + 3, out, nullptr, nullptr, nullptr, x,
        nullptr, nullptr, nullptr);

    (void)in_sizes; (void)n_in; (void)out_size; (void)ws_size;
}